// Round 1
// baseline (497.606 us; speedup 1.0000x reference)
//
#include <hip/hip_runtime.h>
#include <math.h>

#define C_IN 32
#define C2C 64
#define HH 256
#define WW 256

__device__ __forceinline__ float gelu_f(float x) {
    return 0.5f * x * (1.0f + erff(x * 0.70710678118654752f));
}

// cos/sin(2*pi*k/8) tables for dynamic (runtime-lane) indexing
__device__ const float CT8d[8] = {1.0f, 0.70710678118654752f, 0.0f, -0.70710678118654752f,
                                  -1.0f, -0.70710678118654752f, 0.0f, 0.70710678118654752f};
__device__ const float ST8d[8] = {0.0f, 0.70710678118654752f, 1.0f, 0.70710678118654752f,
                                  0.0f, -0.70710678118654752f, -1.0f, -0.70710678118654752f};

// ---------------------------------------------------------------------------
// K1: 1x1 conv in (32->64) + per-8x8-patch rfft2 * fft1 -> gelu -> * fft2 -> irfft2
// One workgroup (512 threads) per (b, hp, wp); thread = (c2, l), l = patch column
// ---------------------------------------------------------------------------
__global__ __launch_bounds__(512)
void k1_spectral(const float* __restrict__ x, const float* __restrict__ w_in,
                 const float* __restrict__ b_in, const float* __restrict__ fft1,
                 const float* __restrict__ fft2, float* __restrict__ z)
{
    constexpr float CT[8] = {1.0f, 0.70710678118654752f, 0.0f, -0.70710678118654752f,
                             -1.0f, -0.70710678118654752f, 0.0f, 0.70710678118654752f};
    constexpr float ST[8] = {0.0f, 0.70710678118654752f, 1.0f, 0.70710678118654752f,
                             0.0f, -0.70710678118654752f, -1.0f, -0.70710678118654752f};

    __shared__ __align__(16) float lw[C2C * C_IN];      // w_in staged: 8 KB
    __shared__ __align__(16) float ubuf[2 * 64 * 68];   // union: x-patch / A / g : 34816 B

    const int tid = threadIdx.x;
    const int c2  = tid >> 3;      // 0..63
    const int l   = tid & 7;       // 0..7

    const int wp = blockIdx.x;     // 0..31
    const int hp = blockIdx.y;     // 0..31
    const int b  = blockIdx.z;     // 0..7
    const int h0 = hp * 8, w0 = wp * 8;

    // ---- stage w_in and x patch (xs[c][w][h] at ubuf[c*96 + w*12 + h]) ----
    for (int i = tid; i < C2C * C_IN; i += 512) lw[i] = w_in[i];
    #pragma unroll
    for (int k = 0; k < 4; ++k) {
        int i = tid + k * 512;             // 0..2047
        int c = i >> 6;
        int rem = i & 63;
        int h = rem >> 3, w = rem & 7;
        float v = x[((b * C_IN + c) * HH + h0 + h) * WW + w0 + w];
        ubuf[c * 96 + w * 12 + h] = v;
    }
    __syncthreads();

    // ---- 1x1 conv: column w=l of patch, channel c2 ----
    float t[8];
    {
        float bv = b_in[c2];
        #pragma unroll
        for (int h = 0; h < 8; ++h) t[h] = bv;
        #pragma unroll
        for (int c = 0; c < C_IN; ++c) {
            float wv = lw[c2 * C_IN + c];
            float4 x0 = *(const float4*)&ubuf[c * 96 + l * 12];
            float4 x1 = *(const float4*)&ubuf[c * 96 + l * 12 + 4];
            t[0] += wv * x0.x; t[1] += wv * x0.y; t[2] += wv * x0.z; t[3] += wv * x0.w;
            t[4] += wv * x1.x; t[5] += wv * x1.y; t[6] += wv * x1.z; t[7] += wv * x1.w;
        }
    }

    // ---- row DFT over h: A[u][w=l] ----
    float Ar[8], Ai[8];
    #pragma unroll
    for (int u = 0; u < 8; ++u) {
        float sr = 0.f, si = 0.f;
        #pragma unroll
        for (int h = 0; h < 8; ++h) {
            const int k = (u * h) & 7;
            sr += t[h] * CT[k];
            si -= t[h] * ST[k];
        }
        Ar[u] = sr; Ai[u] = si;
    }
    __syncthreads();   // all xs reads done -> reuse ubuf for A

    // ---- transpose A via LDS: [c2][u][w], c2-stride 68 ----
    #pragma unroll
    for (int u = 0; u < 8; ++u) {
        ubuf[c2 * 68 + u * 8 + l] = Ar[u];
        ubuf[4352 + c2 * 68 + u * 8 + l] = Ai[u];
    }
    __syncthreads();
    float Ar2[8], Ai2[8];
    {
        float4 r0 = *(const float4*)&ubuf[c2 * 68 + l * 8];
        float4 r1 = *(const float4*)&ubuf[c2 * 68 + l * 8 + 4];
        float4 i0 = *(const float4*)&ubuf[4352 + c2 * 68 + l * 8];
        float4 i1 = *(const float4*)&ubuf[4352 + c2 * 68 + l * 8 + 4];
        Ar2[0]=r0.x; Ar2[1]=r0.y; Ar2[2]=r0.z; Ar2[3]=r0.w;
        Ar2[4]=r1.x; Ar2[5]=r1.y; Ar2[6]=r1.z; Ar2[7]=r1.w;
        Ai2[0]=i0.x; Ai2[1]=i0.y; Ai2[2]=i0.z; Ai2[3]=i0.w;
        Ai2[4]=i1.x; Ai2[5]=i1.y; Ai2[6]=i1.z; Ai2[7]=i1.w;
    }

    // ---- column DFT (v=0..4), filter * fft1, gelu, * fft2 ; role u = l ----
    float gr[5], gi[5];
    #pragma unroll
    for (int v = 0; v < 5; ++v) {
        float fr = 0.f, fi = 0.f;
        #pragma unroll
        for (int w = 0; w < 8; ++w) {
            const int k = (v * w) & 7;
            fr += Ar2[w] * CT[k] + Ai2[w] * ST[k];
            fi += Ai2[w] * CT[k] - Ar2[w] * ST[k];
        }
        float s1 = fft1[(c2 * 8 + l) * 5 + v];
        float s2 = fft2[(c2 * 8 + l) * 5 + v];
        gr[v] = gelu_f(fr * s1) * s2;
        gi[v] = gelu_f(fi * s1) * s2;
    }
    __syncthreads();   // all A reads done -> reuse ubuf for g

    // ---- stash g: float2 at ubuf[c2*82 + (u*5+v)*2], u = l ----
    #pragma unroll
    for (int v = 0; v < 5; ++v) {
        *(float2*)&ubuf[c2 * 82 + (l * 5 + v) * 2] = make_float2(gr[v], gi[v]);
    }
    __syncthreads();

    // ---- inverse: role h = l.  Rr/Ri[h][v] = sum_u g[u][v] * e^{+2pi i u h/8} ----
    float Rr[5] = {0.f,0.f,0.f,0.f,0.f};
    float Ri[5] = {0.f,0.f,0.f,0.f,0.f};
    #pragma unroll
    for (int u = 0; u < 8; ++u) {
        const int k = (u * l) & 7;         // runtime lane index -> rodata table
        float cu = CT8d[k], su = ST8d[k];
        #pragma unroll
        for (int v = 0; v < 5; ++v) {
            float2 g = *(const float2*)&ubuf[c2 * 82 + (u * 5 + v) * 2];
            Rr[v] += g.x * cu - g.y * su;
            Ri[v] += g.x * su + g.y * cu;
        }
    }
    // out[h][w] = (1/64) * sum_v m_v (Rr cos(2pi v w/8) - Ri sin(2pi v w/8))
    float o[8];
    #pragma unroll
    for (int w = 0; w < 8; ++w) {
        float s = 0.f;
        #pragma unroll
        for (int v = 0; v < 5; ++v) {
            const float m = (v == 0 || v == 4) ? 1.0f : 2.0f;
            const int k = (v * w) & 7;
            s += m * (Rr[v] * CT[k] - Ri[v] * ST[k]);
        }
        o[w] = s * 0.015625f;   // 1/64
    }
    float* zp = &z[((b * C2C + c2) * HH + h0 + l) * WW + w0];
    *(float4*)&zp[0] = make_float4(o[0], o[1], o[2], o[3]);
    *(float4*)&zp[4] = make_float4(o[4], o[5], o[6], o[7]);
}

// ---------------------------------------------------------------------------
// K2: 7x7 depthwise conv (pad 3) + gelu + 1x1 conv out (64->32) + bias
// 16x16 output tile per 256-thread WG; 16 chunks of 4 c2 (one c2 per wave)
// ---------------------------------------------------------------------------
__global__ __launch_bounds__(256)
void k2_dwconv(const float* __restrict__ z, const float* __restrict__ w_dw,
               const float* __restrict__ b_dw, const float* __restrict__ w_out,
               const float* __restrict__ b_out, float* __restrict__ out)
{
    __shared__ float zs[4 * 22 * 26];     // 9152 B, row stride 26
    __shared__ float gbuf[4 * 16 * 17];   // 4352 B

    const int tid = threadIdx.x;
    const int tx = blockIdx.x, ty = blockIdx.y, b = blockIdx.z;
    const int x0g = tx * 16, y0g = ty * 16;

    // phase-1 roles: wave = c2_local, lane -> (x, y-quartet)
    const int lane = tid & 63;
    const int wv   = tid >> 6;            // 0..3
    const int px_x = lane & 15;
    const int yq   = lane >> 4;           // 0..3
    const int y0   = yq * 4;

    // phase-2 / output roles: thread = pixel
    const int ox = tid & 15, oy = tid >> 4;

    float acc[32];
    #pragma unroll
    for (int c = 0; c < 32; ++c) acc[c] = b_out[c];

    for (int chunk = 0; chunk < 16; ++chunk) {
        __syncthreads();   // protect zs/gbuf from previous iteration's readers
        // ---- stage z chunk: 4 channels, 22x22 halo window, zero-padded ----
        for (int i = tid; i < 4 * 22 * 22; i += 256) {
            int c2l = i / 484;
            int r   = i - c2l * 484;
            int yy  = r / 22;
            int xx  = r - yy * 22;
            int gy = y0g - 3 + yy, gx = x0g - 3 + xx;
            float v = 0.f;
            if (gy >= 0 && gy < HH && gx >= 0 && gx < WW)
                v = z[((b * C2C + chunk * 4 + c2l) * HH + gy) * WW + gx];
            zs[c2l * 572 + yy * 26 + xx] = v;
        }
        __syncthreads();

        // ---- depthwise 7x7 + gelu for channel c2 = chunk*4 + wv ----
        {
            const int c2u = __builtin_amdgcn_readfirstlane(chunk * 4 + wv);
            const float* wd = &w_dw[c2u * 49];
            float a4[4];
            float bd = b_dw[c2u];
            #pragma unroll
            for (int i = 0; i < 4; ++i) a4[i] = bd;
            #pragma unroll
            for (int ry = 0; ry < 10; ++ry) {
                const int row = y0 + ry;
                float v[7];
                #pragma unroll
                for (int kx = 0; kx < 7; ++kx)
                    v[kx] = zs[wv * 572 + row * 26 + px_x + kx];
                #pragma unroll
                for (int i = 0; i < 4; ++i) {
                    const int ky = ry - i;
                    if (ky >= 0 && ky < 7) {
                        float s = 0.f;
                        #pragma unroll
                        for (int kx = 0; kx < 7; ++kx)
                            s += wd[ky * 7 + kx] * v[kx];
                        a4[i] += s;
                    }
                }
            }
            #pragma unroll
            for (int i = 0; i < 4; ++i)
                gbuf[wv * 272 + (y0 + i) * 17 + px_x] = gelu_f(a4[i]);
        }
        __syncthreads();

        // ---- fold chunk into 32 output-channel accumulators (uniform w_out) ----
        #pragma unroll
        for (int c2l = 0; c2l < 4; ++c2l) {
            float gv = gbuf[c2l * 272 + oy * 17 + ox];
            const int c2i = chunk * 4 + c2l;
            #pragma unroll
            for (int c = 0; c < 32; ++c)
                acc[c] += w_out[c * C2C + c2i] * gv;
        }
    }

    #pragma unroll
    for (int c = 0; c < 32; ++c)
        out[((b * C_IN + c) * HH + y0g + oy) * WW + x0g + ox] = acc[c];
}

extern "C" void kernel_launch(void* const* d_in, const int* in_sizes, int n_in,
                              void* d_out, int out_size, void* d_ws, size_t ws_size,
                              hipStream_t stream) {
    const float* x     = (const float*)d_in[0];
    const float* w_in  = (const float*)d_in[1];
    const float* b_in  = (const float*)d_in[2];
    const float* fft1  = (const float*)d_in[3];
    const float* fft2  = (const float*)d_in[4];
    const float* w_dw  = (const float*)d_in[5];
    const float* b_dw  = (const float*)d_in[6];
    const float* w_out = (const float*)d_in[7];
    const float* b_out = (const float*)d_in[8];
    float* outp = (float*)d_out;
    float* z = (float*)d_ws;   // 8*64*256*256 fp32 = 128 MiB intermediate

    dim3 g1(32, 32, 8);
    k1_spectral<<<g1, 512, 0, stream>>>(x, w_in, b_in, fft1, fft2, z);
    dim3 g2(16, 16, 8);
    k2_dwconv<<<g2, 256, 0, stream>>>(z, w_dw, b_dw, w_out, b_out, outp);
}